// Round 28
// baseline (520.800 us; speedup 1.0000x reference)
//
#include <hip/hip_runtime.h>
#include <math.h>

#define DIM    256
#define IDIM   64
#define HEADS  4
#define NSEQ   256
#define SEQLEN 256
#define NTOK   (NSEQ * SEQLEN)
#define EPSLN  1e-5f

typedef __attribute__((ext_vector_type(8))) short bf16x8s;
typedef __attribute__((ext_vector_type(4))) float f32x4;

union BF8 { bf16x8s v; unsigned short u[8]; };

__device__ __forceinline__ float bf2f(unsigned short u) {
    union { unsigned int i; float f; } v; v.i = ((unsigned int)u) << 16; return v.f;
}
__device__ __forceinline__ unsigned short f2bf(float f) {
    union { float f; unsigned int i; } v; v.f = f;
    unsigned int x = v.i;
    return (unsigned short)((x + 0x7fffu + ((x >> 16) & 1u)) >> 16);
}

// Packed weights: 8 slots (pass*4 + {wq,wk,wv,wo}); slots 0-2 have LN gamma folded in.
__device__ bf16x8s g_wpk[8][8192];
// Folded LN affine terms (slots pass*4+{0,1,2}):
//   g_bias[slot][col] = beta @ W[:,col]
//   g_csum[slot][col] = gamma @ W[:,col]
__device__ float g_bias[8][256];
__device__ float g_csum[8][256];

// =====================================================================
// Pack ALL weights once. grid=(32,8): y = slot (pass*4+m).
// Slots 0-2: W'[k][n] = gamma[k] * W[k][n]. Wo (m=3): row-permuted, no gamma.
// =====================================================================
__global__ __launch_bounds__(256) void wpack_all_kernel(
    const float* __restrict__ Wq_i, const float* __restrict__ Wkv_i,
    const float* __restrict__ Wo_i,
    const float* __restrict__ Wq_j, const float* __restrict__ Wkv_j,
    const float* __restrict__ Wo_j,
    const float* __restrict__ gia, const float* __restrict__ gib,
    const float* __restrict__ gja, const float* __restrict__ gjb)
{
    const int slot = blockIdx.y;
    const int pass = slot >> 2, m = slot & 3;
    const float* W; int ldw, col0, perm;
    const float* gam;
    if (m == 0)      { W = pass ? Wq_j  : Wq_i;  ldw = 256; col0 = 0;   perm = 0; gam = pass ? gja : gia; }
    else if (m == 1) { W = pass ? Wkv_j : Wkv_i; ldw = 512; col0 = 0;   perm = 0; gam = pass ? gjb : gib; }
    else if (m == 2) { W = pass ? Wkv_j : Wkv_i; ldw = 512; col0 = 256; perm = 0; gam = pass ? gjb : gib; }
    else             { W = pass ? Wo_j  : Wo_i;  ldw = 256; col0 = 0;   perm = 1; gam = 0; }

    const int gtile = blockIdx.x * 4 + (threadIdx.x >> 6);   // nt*8+kt, 128 tiles
    const int l = threadIdx.x & 63;
    const int nt = gtile >> 3, kt = gtile & 7;
    const int n = nt * 16 + (l & 15);
    const int k0 = kt * 32 + (l >> 4) * 8;
    BF8 o;
#pragma unroll
    for (int j = 0; j < 8; ++j) {
        int k = k0 + j;
        int src = perm ? ((k & 63) * 4 + (k >> 6)) : k;
        float wv = W[(size_t)src * ldw + col0 + n];
        if (gam) wv *= gam[k];
        o.u[j] = f2bf(wv);
    }
    g_wpk[slot][(size_t)gtile * 64 + l] = o.v;
}

// =====================================================================
// g_bias[slot][col] = beta @ W[:,col]; g_csum[slot][col] = gamma @ W[:,col]
// =====================================================================
__global__ __launch_bounds__(256) void bias_kernel(
    const float* __restrict__ bia, const float* __restrict__ bib,
    const float* __restrict__ bja, const float* __restrict__ bjb,
    const float* __restrict__ gia, const float* __restrict__ gib,
    const float* __restrict__ gja, const float* __restrict__ gjb,
    const float* __restrict__ Wq_i, const float* __restrict__ Wkv_i,
    const float* __restrict__ Wq_j, const float* __restrict__ Wkv_j)
{
    const int s = blockIdx.x;          // 0..5
    const int pass = s / 3, m = s % 3;
    const float* beta = (m == 0) ? (pass ? bja : bia) : (pass ? bjb : bib);
    const float* gam  = (m == 0) ? (pass ? gja : gia) : (pass ? gjb : gib);
    const float* W    = (m == 0) ? (pass ? Wq_j : Wq_i) : (pass ? Wkv_j : Wkv_i);
    const int ldw  = (m == 0) ? 256 : 512;
    const int col0 = (m == 2) ? 256 : 0;
    const int col  = threadIdx.x;
    float ab = 0.f, ac = 0.f;
    for (int k = 0; k < 256; ++k) {
        float wv = W[(size_t)k * ldw + col0 + col];
        ab += beta[k] * wv;
        ac += gam[k]  * wv;
    }
    g_bias[pass * 4 + m][col] = ab;
    g_csum[pass * 4 + m][col] = ac;
}

// =====================================================================
// Fused LN + QKV GEMM + RoPE + repack.  1024 threads (16 waves), 32 tokens/block.
// (round-24/25 structure: fused stage+stats, B-dedup, B-dbuf — measured best)
// =====================================================================
#define HLD  264
#define CLD2 261

__global__ __launch_bounds__(1024) void lnqkv_kernel(
    const float* __restrict__ x,
    const float* __restrict__ sin_t, const float* __restrict__ cos_t,
    bf16x8s* __restrict__ qo, bf16x8s* __restrict__ ko, bf16x8s* __restrict__ vo,
    int pass)
{
    __shared__ __align__(16) unsigned short smu[17024];   // 34,048 B
    unsigned short* hi = smu;                       // [0, 16896) B
    unsigned short* lo = smu + 8448;                // [16896, 33792) B
    float* stats = (float*)(smu + 16896);           // rstd[32], murstd[32]
    float* smf = (float*)smu;                       // C f32 [32][261] overlay

    const int tid = threadIdx.x;
    const int l = tid & 63, w = tid >> 6;      // w 0..15
    const int lr = l & 15, lk = l >> 4;
    const int t0 = blockIdx.x * 32;
    const int seq = t0 >> 8;
    const int pos0 = t0 & 255;
    const int wbase = pass * 4;

    // ---- stage + stats fused ----
    {
        const int r  = tid >> 5;          // 0..31
        const int c0 = (tid & 31) * 8;
        int t = t0 + r;
        int row = (pass == 0) ? t : ((t & 255) * NSEQ + (t >> 8));
        const float4* xp = reinterpret_cast<const float4*>(&x[(size_t)row * DIM + c0]);
        float4 v0 = xp[0], v1 = xp[1];
        float vv[8] = {v0.x, v0.y, v0.z, v0.w, v1.x, v1.y, v1.z, v1.w};
        BF8 hh, ll;
        float s1 = 0.f, s2 = 0.f;
#pragma unroll
        for (int j = 0; j < 8; ++j) {
            union { float f; unsigned int u; } a; a.f = vv[j];
            unsigned short h = (unsigned short)(a.u >> 16);   // truncation split
            hh.u[j] = h;
            ll.u[j] = f2bf(vv[j] - bf2f(h));
            float v = bf2f(hh.u[j]) + bf2f(ll.u[j]);
            s1 += v; s2 += v * v;
        }
        *reinterpret_cast<bf16x8s*>(hi + r * HLD + c0) = hh.v;
        *reinterpret_cast<bf16x8s*>(lo + r * HLD + c0) = ll.v;
        for (int off = 1; off < 32; off <<= 1) {
            s1 += __shfl_xor(s1, off, 32);
            s2 += __shfl_xor(s2, off, 32);
        }
        float mu = s1 * (1.f / 256.f);
        float var = s2 * (1.f / 256.f) - mu * mu;
        float rstd = rsqrtf(var + EPSLN);
        if ((tid & 31) == 0) { stats[r] = rstd; stats[32 + r] = mu * rstd; }
    }
    __syncthreads();

    // ---- K-loop: ds_read + MFMA with B double-buffer ----
    f32x4 acc[2][3];
#pragma unroll
    for (int mp2 = 0; mp2 < 2; ++mp2)
#pragma unroll
        for (int nf = 0; nf < 3; ++nf) { f32x4 z = {0.f, 0.f, 0.f, 0.f}; acc[mp2][nf] = z; }

    const int nt0 = w * 3;

    bf16x8s bcur[3];
#pragma unroll
    for (int nf = 0; nf < 3; ++nf) {
        const int ntg = nt0 + nf;
        bcur[nf] = g_wpk[wbase + (ntg >> 4)][((size_t)((ntg & 15) * 8 + 0)) * 64 + l];
    }

    for (int ks = 0; ks < 8; ++ks) {
        bf16x8s bnext[3];
        if (ks < 7) {
#pragma unroll
            for (int nf = 0; nf < 3; ++nf) {
                const int ntg = nt0 + nf;
                bnext[nf] = g_wpk[wbase + (ntg >> 4)][((size_t)((ntg & 15) * 8 + (ks + 1))) * 64 + l];
            }
        }
        const int c0 = ks * 32 + lk * 8;
#pragma unroll
        for (int mp2 = 0; mp2 < 2; ++mp2) {
            const int arow = mp2 * 16 + lr;
            const bf16x8s ahi = *(const bf16x8s*)(hi + arow * HLD + c0);
            const bf16x8s alo = *(const bf16x8s*)(lo + arow * HLD + c0);
#pragma unroll
            for (int nf = 0; nf < 3; ++nf) {
                acc[mp2][nf] = __builtin_amdgcn_mfma_f32_16x16x32_bf16(alo, bcur[nf], acc[mp2][nf], 0, 0, 0);
                acc[mp2][nf] = __builtin_amdgcn_mfma_f32_16x16x32_bf16(ahi, bcur[nf], acc[mp2][nf], 0, 0, 0);
            }
        }
        if (ks < 7) {
#pragma unroll
            for (int nf = 0; nf < 3; ++nf) bcur[nf] = bnext[nf];
        }
    }
    __syncthreads();   // hi/lo dead from here (stats region preserved)

    // ---- three C chunks (q, k, v); epilogue applies affine + bias (+RoPE) ----
    for (int c = 0; c < 3; ++c) {
#pragma unroll
        for (int nf = 0; nf < 3; ++nf) {
            int ntg = nt0 + nf;
            if ((ntg >> 4) == c) {
                int cb = (ntg & 15) * 16 + lr;
#pragma unroll
                for (int mp2 = 0; mp2 < 2; ++mp2)
#pragma unroll
                    for (int r = 0; r < 4; ++r)
                        smf[(mp2 * 16 + lk * 4 + r) * CLD2 + cb] = acc[mp2][nf][r];
            }
        }
        __syncthreads();

        // epilogue: 16 tiles, 1 per wave
        if (c < 2) {
            // q or k: affine + RoPE, pack-A
            int h = w >> 2, mt = (w >> 1) & 1, ktd = w & 1;
            int row = mt * 16 + lr;
            int pos = pos0 + row;
            int d0 = ktd * 32 + lk * 8;
            const float* src = &smf[row * CLD2 + h * 64 + d0];
            const float* bv = &g_bias[wbase + c][h * 64 + d0];
            const float* cv = &g_csum[wbase + c][h * 64 + d0];
            float rs = stats[row], mr = stats[32 + row];
            BF8 o;
#pragma unroll
            for (int p2 = 0; p2 < 4; ++p2) {
                float cs = cos_t[pos * IDIM + d0 + 2 * p2];
                float sn = sin_t[pos * IDIM + d0 + 2 * p2];
                float e  = rs * src[2 * p2]     - mr * cv[2 * p2]     + bv[2 * p2];
                float od = rs * src[2 * p2 + 1] - mr * cv[2 * p2 + 1] + bv[2 * p2 + 1];
                o.u[2 * p2]     = f2bf(e * cs - od * sn);
                o.u[2 * p2 + 1] = f2bf(od * cs + e * sn);
            }
            int sh = seq * 4 + h;
            int mtg = (pos0 >> 4) + mt;
            bf16x8s* dst = c ? ko : qo;
            dst[((size_t)sh * 32 + mtg * 2 + ktd) * 64 + l] = o.v;
        } else {
            // v: affine, pack-B over [kpos][d]
            int h = w >> 2, ntd = w & 3;
            int col = h * 64 + ntd * 16 + lr;
            float bb_ = g_bias[wbase + 2][col];
            float cc_ = g_csum[wbase + 2][col];
            BF8 o;
#pragma unroll
            for (int j = 0; j < 8; ++j) {
                int rr = lk * 8 + j;
                o.u[j] = f2bf(stats[rr] * smf[rr * CLD2 + col] - stats[32 + rr] * cc_ + bb_);
            }
            int sh = seq * 4 + h;
            int ktg = pos0 >> 5;
            vo[((size_t)sh * 32 + ktg * 4 + ntd) * 64 + l] = o.v;
        }
        __syncthreads();
    }
}

// =====================================================================
// Attention: block = (seq,head), 512 threads (8 waves x 32 q-rows).
// BARRIER-FREE: the P tile round-trip is wave-local. Waves free-run at
// divergent phases -> T5 s_setprio(1) around MFMA clusters (m191: +4-7%
// on independently-phased attn; hint-only, no semantic change).
// P tile in LDS bf16, 16B XOR swizzle (byte ^= (row&7)<<4).
// =====================================================================
__global__ __launch_bounds__(512) void attn_kernel(
    const bf16x8s* __restrict__ qpk, const bf16x8s* __restrict__ kpk,
    const bf16x8s* __restrict__ vpk, bf16x8s* __restrict__ opk)
{
    __shared__ __align__(16) unsigned short Pus[256 * 64];   // 32,768 B
    char* Pb = (char*)Pus;
    const int tid = threadIdx.x, l = tid & 63, w = tid >> 6;   // w 0..7
    const int lr = l & 15, lk = l >> 4;
    const int sh = blockIdx.x;
    const size_t base = (size_t)sh * 32 * 64;

    bf16x8s qf[2][2];
#pragma unroll
    for (int mf = 0; mf < 2; ++mf)
#pragma unroll
        for (int kt = 0; kt < 2; ++kt)
            qf[mf][kt] = qpk[base + ((size_t)((w * 2 + mf) * 2 + kt)) * 64 + l];

    f32x4 O[2][4];
    float mrun[2][4], lrun[2][4];
#pragma unroll
    for (int mf = 0; mf < 2; ++mf)
#pragma unroll
        for (int nf = 0; nf < 4; ++nf) { f32x4 z = {0.f, 0.f, 0.f, 0.f}; O[mf][nf] = z; }
#pragma unroll
    for (int mf = 0; mf < 2; ++mf)
#pragma unroll
        for (int r = 0; r < 4; ++r) { mrun[mf][r] = -1e30f; lrun[mf][r] = 0.f; }

    for (int ktk = 0; ktk < 4; ++ktk) {
#pragma unroll
        for (int mf = 0; mf < 2; ++mf) {
            f32x4 S[4];
#pragma unroll
            for (int nf = 0; nf < 4; ++nf) { f32x4 z = {0.f, 0.f, 0.f, 0.f}; S[nf] = z; }
#pragma unroll
            for (int ks = 0; ks < 2; ++ks) {
                bf16x8s kf[4];
#pragma unroll
                for (int nf = 0; nf < 4; ++nf)
                    kf[nf] = kpk[base + ((size_t)((ktk * 4 + nf) * 2 + ks)) * 64 + l];
                __builtin_amdgcn_s_setprio(1);
#pragma unroll
                for (int nf = 0; nf < 4; ++nf)
                    S[nf] = __builtin_amdgcn_mfma_f32_16x16x32_bf16(qf[mf][ks], kf[nf], S[nf], 0, 0, 0);
                __builtin_amdgcn_s_setprio(0);
            }
            // online softmax per row
#pragma unroll
            for (int r = 0; r < 4; ++r) {
                float mt_ = fmaxf(fmaxf(S[0][r], S[1][r]), fmaxf(S[2][r], S[3][r]));
                for (int off = 1; off < 16; off <<= 1) mt_ = fmaxf(mt_, __shfl_xor(mt_, off, 64));
                float mnew = fmaxf(mrun[mf][r], mt_);
                float sc = __expf(mrun[mf][r] - mnew);
#pragma unroll
                for (int nf = 0; nf < 4; ++nf) O[mf][nf][r] *= sc;
                float ps = 0.f;
#pragma unroll
                for (int nf = 0; nf < 4; ++nf) {
                    float pp = __expf(S[nf][r] - mnew);
                    S[nf][r] = pp;
                    ps += pp;
                }
                for (int off = 1; off < 16; off <<= 1) ps += __shfl_xor(ps, off, 64);
                lrun[mf][r] = lrun[mf][r] * sc + ps;
                mrun[mf][r] = mnew;
            }
            // P -> LDS (bf16, swizzled) — wave-local rows
#pragma unroll
            for (int nf = 0; nf < 4; ++nf)
#pragma unroll
                for (int r = 0; r < 4; ++r) {
                    int row = w * 32 + mf * 16 + lk * 4 + r, col = nf * 16 + lr;
                    unsigned int byte = ((unsigned)(row * 64 + col) * 2) ^ (unsigned)((row & 7) << 4);
                    *(unsigned short*)(Pb + byte) = f2bf(S[nf][r]);
                }
        }
        // PV: reads only this wave's rows — no barrier needed
#pragma unroll
        for (int ks = 0; ks < 2; ++ks) {
            bf16x8s vf[4];
#pragma unroll
            for (int nf = 0; nf < 4; ++nf)
                vf[nf] = vpk[base + ((size_t)((ktk * 2 + ks) * 4 + nf)) * 64 + l];
#pragma unroll
            for (int mf = 0; mf < 2; ++mf) {
                int row = w * 32 + mf * 16 + lr;
                unsigned int byte = ((unsigned)(row * 64 + ks * 32 + lk * 8) * 2) ^ (unsigned)((row & 7) << 4);
                bf16x8s pa = *(const bf16x8s*)(Pb + byte);
                __builtin_amdgcn_s_setprio(1);
#pragma unroll
                for (int nf = 0; nf < 4; ++nf)
                    O[mf][nf] = __builtin_amdgcn_mfma_f32_16x16x32_bf16(pa, vf[nf], O[mf][nf], 0, 0, 0);
                __builtin_amdgcn_s_setprio(0);
            }
        }
    }

    // normalize -> LDS (bf16, swizzled) -> pack out (wave-local rows, no barrier)
#pragma unroll
    for (int mf = 0; mf < 2; ++mf)
#pragma unroll
        for (int r = 0; r < 4; ++r) {
            float inv = 1.f / lrun[mf][r];
#pragma unroll
            for (int nf = 0; nf < 4; ++nf) {
                int row = w * 32 + mf * 16 + lk * 4 + r, col = nf * 16 + lr;
                unsigned int byte = ((unsigned)(row * 64 + col) * 2) ^ (unsigned)((row & 7) << 4);
                *(unsigned short*)(Pb + byte) = f2bf(O[mf][nf][r] * inv);
            }
        }
    const int seq = sh >> 2, h = sh & 3;
#pragma unroll
    for (int mf = 0; mf < 2; ++mf)
#pragma unroll
        for (int ktd = 0; ktd < 2; ++ktd) {
            int row = w * 32 + mf * 16 + lr;
            unsigned int byte = ((unsigned)(row * 64 + ktd * 32 + lk * 8) * 2) ^ (unsigned)((row & 7) << 4);
            bf16x8s o = *(const bf16x8s*)(Pb + byte);
            size_t mtg = (size_t)seq * 16 + w * 2 + mf;
            opk[(mtg * 8 + h * 2 + ktd) * 64 + l] = o;
        }
}

// =====================================================================
// Proj GEMM: grid 1024 blocks x 512 threads; block = 64 rows x 256 cols via
// an in-block 2-phase nb loop. Wave = 1 m-tile x 4 n-tiles (acc[4], no LDS).
// Direct register epilogue.
// =====================================================================
__global__ __launch_bounds__(512) void gemm_proj_kernel(
    const bf16x8s* __restrict__ A,
    const float* __restrict__ x, const float* __restrict__ bo,
    float* __restrict__ out, int pass)
{
    const int tid = threadIdx.x;
    const int l = tid & 63, w = tid >> 6;       // w 0..7
    const int wm = w >> 1, wn = w & 1;          // wm 0..3 (16-row m-tiles), wn 0..1 (64-col strips)
    const int mb = blockIdx.x;                  // 1024 blocks, 64 rows each
    const bf16x8s* B = g_wpk[pass * 4 + 3];
    const int mt0 = mb * 4 + wm;

#pragma unroll 1
    for (int nb = 0; nb < 2; ++nb) {
        f32x4 acc[4];
#pragma unroll
        for (int nf = 0; nf < 4; ++nf) { f32x4 z = {0.f, 0.f, 0.f, 0.f}; acc[nf] = z; }

        const int nt0 = nb * 8 + wn * 4;
#pragma unroll
        for (int ks = 0; ks < 8; ++ks) {
            bf16x8s a = A[((size_t)mt0 * 8 + ks) * 64 + l];
            bf16x8s b[4];
#pragma unroll
            for (int nf = 0; nf < 4; ++nf) b[nf] = B[((size_t)(nt0 + nf) * 8 + ks) * 64 + l];
#pragma unroll
            for (int nf = 0; nf < 4; ++nf)
                acc[nf] = __builtin_amdgcn_mfma_f32_16x16x32_bf16(a, b[nf], acc[nf], 0, 0, 0);
        }

        // direct epilogue from registers: bias + ELU + residual
#pragma unroll
        for (int nf = 0; nf < 4; ++nf) {
            const int col = nb * 128 + wn * 64 + nf * 16 + (l & 15);
            const float bc = bo[col];
#pragma unroll
            for (int r = 0; r < 4; ++r) {
                int row = mb * 64 + wm * 16 + (l >> 4) * 4 + r;
                size_t prow = (pass == 0) ? (size_t)row
                                          : ((size_t)(row & 255) * NSEQ + (row >> 8));
                size_t addr = prow * DIM + col;
                float y = acc[nf][r] + bc;
                float e = 0.5f * (y > 0.f ? y : expm1f(y));
                if (pass == 0) out[addr] = x[addr] + e;
                else           out[addr] += e;
            }
        }
    }
}

// =====================================================================
extern "C" void kernel_launch(void* const* d_in, const int* in_sizes, int n_in,
                              void* d_out, int out_size, void* d_ws, size_t ws_size,
                              hipStream_t stream) {
    const float* x     = (const float*)d_in[0];
    const float* sin_i = (const float*)d_in[1];
    const float* cos_i = (const float*)d_in[2];
    const float* sin_j = (const float*)d_in[3];
    const float* cos_j = (const float*)d_in[4];
    const float* gia   = (const float*)d_in[5];
    const float* bia   = (const float*)d_in[6];
    const float* gib   = (const float*)d_in[7];
    const float* bib   = (const float*)d_in[8];
    const float* Wq_i  = (const float*)d_in[9];
    const float* Wkv_i = (const float*)d_in[10];
    const float* Wo_i  = (const float*)d_in[11];
    const float* bo_i  = (const float*)d_in[12];
    const float* gja   = (const float*)d_in[13];
    const float* bja   = (const float*)d_in[14];
    const float* gjb   = (const float*)d_in[15];
    const float* bjb   = (const float*)d_in[16];
    const float* Wq_j  = (const float*)d_in[17];
    const float* Wkv_j = (const float*)d_in[18];
    const float* Wo_j  = (const float*)d_in[19];
    const float* bo_j  = (const float*)d_in[20];

    float* out = (float*)d_out;

    char* base = (char*)d_ws;
    const size_t MB32 = 33554432;
    bf16x8s* buf0 = (bf16x8s*)(base);             // v
    bf16x8s* buf1 = (bf16x8s*)(base + MB32);      // o
    bf16x8s* buf2 = (bf16x8s*)(base + 2 * MB32);  // q
    bf16x8s* buf3 = (bf16x8s*)(base + 3 * MB32);  // k

    // pack all weights (gamma folded) + fold beta/gamma into bias/csum vectors
    wpack_all_kernel<<<dim3(32, 8), 256, 0, stream>>>(
        Wq_i, Wkv_i, Wo_i, Wq_j, Wkv_j, Wo_j, gia, gib, gja, gjb);
    bias_kernel<<<6, 256, 0, stream>>>(
        bia, bib, bja, bjb, gia, gib, gja, gjb, Wq_i, Wkv_i, Wq_j, Wkv_j);

    for (int pass = 0; pass < 2; ++pass) {
        const float* sin_t = pass ? sin_j : sin_i;
        const float* cos_t = pass ? cos_j : cos_i;
        const float* bo = pass ? bo_j : bo_i;

        // fused LN + QKV + RoPE + repack: q->buf2, k->buf3, v->buf0
        lnqkv_kernel<<<2048, 1024, 0, stream>>>(
            x, sin_t, cos_t, buf2, buf3, buf0, pass);
        // attn: q,k,v -> o (buf1)
        attn_kernel<<<1024, 512, 0, stream>>>(buf2, buf3, buf0, buf1);
        // proj + residual
        gemm_proj_kernel<<<1024, 512, 0, stream>>>(buf1, x, bo, out, pass);
    }
}

// Round 29
// 509.468 us; speedup vs baseline: 1.0222x; 1.0222x over previous
//
#include <hip/hip_runtime.h>
#include <math.h>

#define DIM    256
#define IDIM   64
#define HEADS  4
#define NSEQ   256
#define SEQLEN 256
#define NTOK   (NSEQ * SEQLEN)
#define EPSLN  1e-5f

typedef __attribute__((ext_vector_type(8))) short bf16x8s;
typedef __attribute__((ext_vector_type(4))) float f32x4;

union BF8 { bf16x8s v; unsigned short u[8]; };

__device__ __forceinline__ float bf2f(unsigned short u) {
    union { unsigned int i; float f; } v; v.i = ((unsigned int)u) << 16; return v.f;
}
__device__ __forceinline__ unsigned short f2bf(float f) {
    union { float f; unsigned int i; } v; v.f = f;
    unsigned int x = v.i;
    return (unsigned short)((x + 0x7fffu + ((x >> 16) & 1u)) >> 16);
}

// Packed weights: 8 slots (pass*4 + {wq,wk,wv,wo}); slots 0-2 have LN gamma folded in.
__device__ bf16x8s g_wpk[8][8192];
// Folded LN affine terms (slots pass*4+{0,1,2}):
//   g_bias[slot][col] = beta @ W[:,col]
//   g_csum[slot][col] = gamma @ W[:,col]
__device__ float g_bias[8][256];
__device__ float g_csum[8][256];

// =====================================================================
// Pack ALL weights once. grid=(32,8): y = slot (pass*4+m).
// Slots 0-2: W'[k][n] = gamma[k] * W[k][n]. Wo (m=3): row-permuted, no gamma.
// =====================================================================
__global__ __launch_bounds__(256) void wpack_all_kernel(
    const float* __restrict__ Wq_i, const float* __restrict__ Wkv_i,
    const float* __restrict__ Wo_i,
    const float* __restrict__ Wq_j, const float* __restrict__ Wkv_j,
    const float* __restrict__ Wo_j,
    const float* __restrict__ gia, const float* __restrict__ gib,
    const float* __restrict__ gja, const float* __restrict__ gjb)
{
    const int slot = blockIdx.y;
    const int pass = slot >> 2, m = slot & 3;
    const float* W; int ldw, col0, perm;
    const float* gam;
    if (m == 0)      { W = pass ? Wq_j  : Wq_i;  ldw = 256; col0 = 0;   perm = 0; gam = pass ? gja : gia; }
    else if (m == 1) { W = pass ? Wkv_j : Wkv_i; ldw = 512; col0 = 0;   perm = 0; gam = pass ? gjb : gib; }
    else if (m == 2) { W = pass ? Wkv_j : Wkv_i; ldw = 512; col0 = 256; perm = 0; gam = pass ? gjb : gib; }
    else             { W = pass ? Wo_j  : Wo_i;  ldw = 256; col0 = 0;   perm = 1; gam = 0; }

    const int gtile = blockIdx.x * 4 + (threadIdx.x >> 6);   // nt*8+kt, 128 tiles
    const int l = threadIdx.x & 63;
    const int nt = gtile >> 3, kt = gtile & 7;
    const int n = nt * 16 + (l & 15);
    const int k0 = kt * 32 + (l >> 4) * 8;
    BF8 o;
#pragma unroll
    for (int j = 0; j < 8; ++j) {
        int k = k0 + j;
        int src = perm ? ((k & 63) * 4 + (k >> 6)) : k;
        float wv = W[(size_t)src * ldw + col0 + n];
        if (gam) wv *= gam[k];
        o.u[j] = f2bf(wv);
    }
    g_wpk[slot][(size_t)gtile * 64 + l] = o.v;
}

// =====================================================================
// g_bias[slot][col] = beta @ W[:,col]; g_csum[slot][col] = gamma @ W[:,col]
// =====================================================================
__global__ __launch_bounds__(256) void bias_kernel(
    const float* __restrict__ bia, const float* __restrict__ bib,
    const float* __restrict__ bja, const float* __restrict__ bjb,
    const float* __restrict__ gia, const float* __restrict__ gib,
    const float* __restrict__ gja, const float* __restrict__ gjb,
    const float* __restrict__ Wq_i, const float* __restrict__ Wkv_i,
    const float* __restrict__ Wq_j, const float* __restrict__ Wkv_j)
{
    const int s = blockIdx.x;          // 0..5
    const int pass = s / 3, m = s % 3;
    const float* beta = (m == 0) ? (pass ? bja : bia) : (pass ? bjb : bib);
    const float* gam  = (m == 0) ? (pass ? gja : gia) : (pass ? gjb : gib);
    const float* W    = (m == 0) ? (pass ? Wq_j : Wq_i) : (pass ? Wkv_j : Wkv_i);
    const int ldw  = (m == 0) ? 256 : 512;
    const int col0 = (m == 2) ? 256 : 0;
    const int col  = threadIdx.x;
    float ab = 0.f, ac = 0.f;
    for (int k = 0; k < 256; ++k) {
        float wv = W[(size_t)k * ldw + col0 + col];
        ab += beta[k] * wv;
        ac += gam[k]  * wv;
    }
    g_bias[pass * 4 + m][col] = ab;
    g_csum[pass * 4 + m][col] = ac;
}

// =====================================================================
// Fused LN + QKV GEMM + RoPE + repack.  1024 threads (16 waves), 32 tokens/block.
// (round-24/25 structure: fused stage+stats, B-dedup, B-dbuf — measured best)
// =====================================================================
#define HLD  264
#define CLD2 261

__global__ __launch_bounds__(1024) void lnqkv_kernel(
    const float* __restrict__ x,
    const float* __restrict__ sin_t, const float* __restrict__ cos_t,
    bf16x8s* __restrict__ qo, bf16x8s* __restrict__ ko, bf16x8s* __restrict__ vo,
    int pass)
{
    __shared__ __align__(16) unsigned short smu[17024];   // 34,048 B
    unsigned short* hi = smu;                       // [0, 16896) B
    unsigned short* lo = smu + 8448;                // [16896, 33792) B
    float* stats = (float*)(smu + 16896);           // rstd[32], murstd[32]
    float* smf = (float*)smu;                       // C f32 [32][261] overlay

    const int tid = threadIdx.x;
    const int l = tid & 63, w = tid >> 6;      // w 0..15
    const int lr = l & 15, lk = l >> 4;
    const int t0 = blockIdx.x * 32;
    const int seq = t0 >> 8;
    const int pos0 = t0 & 255;
    const int wbase = pass * 4;

    // ---- stage + stats fused ----
    {
        const int r  = tid >> 5;          // 0..31
        const int c0 = (tid & 31) * 8;
        int t = t0 + r;
        int row = (pass == 0) ? t : ((t & 255) * NSEQ + (t >> 8));
        const float4* xp = reinterpret_cast<const float4*>(&x[(size_t)row * DIM + c0]);
        float4 v0 = xp[0], v1 = xp[1];
        float vv[8] = {v0.x, v0.y, v0.z, v0.w, v1.x, v1.y, v1.z, v1.w};
        BF8 hh, ll;
        float s1 = 0.f, s2 = 0.f;
#pragma unroll
        for (int j = 0; j < 8; ++j) {
            union { float f; unsigned int u; } a; a.f = vv[j];
            unsigned short h = (unsigned short)(a.u >> 16);   // truncation split
            hh.u[j] = h;
            ll.u[j] = f2bf(vv[j] - bf2f(h));
            float v = bf2f(hh.u[j]) + bf2f(ll.u[j]);
            s1 += v; s2 += v * v;
        }
        *reinterpret_cast<bf16x8s*>(hi + r * HLD + c0) = hh.v;
        *reinterpret_cast<bf16x8s*>(lo + r * HLD + c0) = ll.v;
        for (int off = 1; off < 32; off <<= 1) {
            s1 += __shfl_xor(s1, off, 32);
            s2 += __shfl_xor(s2, off, 32);
        }
        float mu = s1 * (1.f / 256.f);
        float var = s2 * (1.f / 256.f) - mu * mu;
        float rstd = rsqrtf(var + EPSLN);
        if ((tid & 31) == 0) { stats[r] = rstd; stats[32 + r] = mu * rstd; }
    }
    __syncthreads();

    // ---- K-loop: ds_read + MFMA with B double-buffer ----
    f32x4 acc[2][3];
#pragma unroll
    for (int mp2 = 0; mp2 < 2; ++mp2)
#pragma unroll
        for (int nf = 0; nf < 3; ++nf) { f32x4 z = {0.f, 0.f, 0.f, 0.f}; acc[mp2][nf] = z; }

    const int nt0 = w * 3;

    bf16x8s bcur[3];
#pragma unroll
    for (int nf = 0; nf < 3; ++nf) {
        const int ntg = nt0 + nf;
        bcur[nf] = g_wpk[wbase + (ntg >> 4)][((size_t)((ntg & 15) * 8 + 0)) * 64 + l];
    }

    for (int ks = 0; ks < 8; ++ks) {
        bf16x8s bnext[3];
        if (ks < 7) {
#pragma unroll
            for (int nf = 0; nf < 3; ++nf) {
                const int ntg = nt0 + nf;
                bnext[nf] = g_wpk[wbase + (ntg >> 4)][((size_t)((ntg & 15) * 8 + (ks + 1))) * 64 + l];
            }
        }
        const int c0 = ks * 32 + lk * 8;
#pragma unroll
        for (int mp2 = 0; mp2 < 2; ++mp2) {
            const int arow = mp2 * 16 + lr;
            const bf16x8s ahi = *(const bf16x8s*)(hi + arow * HLD + c0);
            const bf16x8s alo = *(const bf16x8s*)(lo + arow * HLD + c0);
#pragma unroll
            for (int nf = 0; nf < 3; ++nf) {
                acc[mp2][nf] = __builtin_amdgcn_mfma_f32_16x16x32_bf16(alo, bcur[nf], acc[mp2][nf], 0, 0, 0);
                acc[mp2][nf] = __builtin_amdgcn_mfma_f32_16x16x32_bf16(ahi, bcur[nf], acc[mp2][nf], 0, 0, 0);
            }
        }
        if (ks < 7) {
#pragma unroll
            for (int nf = 0; nf < 3; ++nf) bcur[nf] = bnext[nf];
        }
    }
    __syncthreads();   // hi/lo dead from here (stats region preserved)

    // ---- three C chunks (q, k, v); epilogue applies affine + bias (+RoPE) ----
    for (int c = 0; c < 3; ++c) {
#pragma unroll
        for (int nf = 0; nf < 3; ++nf) {
            int ntg = nt0 + nf;
            if ((ntg >> 4) == c) {
                int cb = (ntg & 15) * 16 + lr;
#pragma unroll
                for (int mp2 = 0; mp2 < 2; ++mp2)
#pragma unroll
                    for (int r = 0; r < 4; ++r)
                        smf[(mp2 * 16 + lk * 4 + r) * CLD2 + cb] = acc[mp2][nf][r];
            }
        }
        __syncthreads();

        // epilogue: 16 tiles, 1 per wave
        if (c < 2) {
            // q or k: affine + RoPE, pack-A
            int h = w >> 2, mt = (w >> 1) & 1, ktd = w & 1;
            int row = mt * 16 + lr;
            int pos = pos0 + row;
            int d0 = ktd * 32 + lk * 8;
            const float* src = &smf[row * CLD2 + h * 64 + d0];
            const float* bv = &g_bias[wbase + c][h * 64 + d0];
            const float* cv = &g_csum[wbase + c][h * 64 + d0];
            float rs = stats[row], mr = stats[32 + row];
            BF8 o;
#pragma unroll
            for (int p2 = 0; p2 < 4; ++p2) {
                float cs = cos_t[pos * IDIM + d0 + 2 * p2];
                float sn = sin_t[pos * IDIM + d0 + 2 * p2];
                float e  = rs * src[2 * p2]     - mr * cv[2 * p2]     + bv[2 * p2];
                float od = rs * src[2 * p2 + 1] - mr * cv[2 * p2 + 1] + bv[2 * p2 + 1];
                o.u[2 * p2]     = f2bf(e * cs - od * sn);
                o.u[2 * p2 + 1] = f2bf(od * cs + e * sn);
            }
            int sh = seq * 4 + h;
            int mtg = (pos0 >> 4) + mt;
            bf16x8s* dst = c ? ko : qo;
            dst[((size_t)sh * 32 + mtg * 2 + ktd) * 64 + l] = o.v;
        } else {
            // v: affine, pack-B over [kpos][d]
            int h = w >> 2, ntd = w & 3;
            int col = h * 64 + ntd * 16 + lr;
            float bb_ = g_bias[wbase + 2][col];
            float cc_ = g_csum[wbase + 2][col];
            BF8 o;
#pragma unroll
            for (int j = 0; j < 8; ++j) {
                int rr = lk * 8 + j;
                o.u[j] = f2bf(stats[rr] * smf[rr * CLD2 + col] - stats[32 + rr] * cc_ + bb_);
            }
            int sh = seq * 4 + h;
            int ktg = pos0 >> 5;
            vo[((size_t)sh * 32 + ktg * 4 + ntd) * 64 + l] = o.v;
        }
        __syncthreads();
    }
}

// =====================================================================
// Attention: block = (seq,head), 512 threads (8 waves x 32 q-rows).
// BARRIER-FREE: the P tile round-trip is wave-local.
// P tile in LDS bf16, 16B XOR swizzle (byte ^= (row&7)<<4).
// =====================================================================
__global__ __launch_bounds__(512) void attn_kernel(
    const bf16x8s* __restrict__ qpk, const bf16x8s* __restrict__ kpk,
    const bf16x8s* __restrict__ vpk, bf16x8s* __restrict__ opk)
{
    __shared__ __align__(16) unsigned short Pus[256 * 64];   // 32,768 B
    char* Pb = (char*)Pus;
    const int tid = threadIdx.x, l = tid & 63, w = tid >> 6;   // w 0..7
    const int lr = l & 15, lk = l >> 4;
    const int sh = blockIdx.x;
    const size_t base = (size_t)sh * 32 * 64;

    bf16x8s qf[2][2];
#pragma unroll
    for (int mf = 0; mf < 2; ++mf)
#pragma unroll
        for (int kt = 0; kt < 2; ++kt)
            qf[mf][kt] = qpk[base + ((size_t)((w * 2 + mf) * 2 + kt)) * 64 + l];

    f32x4 O[2][4];
    float mrun[2][4], lrun[2][4];
#pragma unroll
    for (int mf = 0; mf < 2; ++mf)
#pragma unroll
        for (int nf = 0; nf < 4; ++nf) { f32x4 z = {0.f, 0.f, 0.f, 0.f}; O[mf][nf] = z; }
#pragma unroll
    for (int mf = 0; mf < 2; ++mf)
#pragma unroll
        for (int r = 0; r < 4; ++r) { mrun[mf][r] = -1e30f; lrun[mf][r] = 0.f; }

    for (int ktk = 0; ktk < 4; ++ktk) {
#pragma unroll
        for (int mf = 0; mf < 2; ++mf) {
            f32x4 S[4];
#pragma unroll
            for (int nf = 0; nf < 4; ++nf) { f32x4 z = {0.f, 0.f, 0.f, 0.f}; S[nf] = z; }
#pragma unroll
            for (int ks = 0; ks < 2; ++ks) {
                bf16x8s kf[4];
#pragma unroll
                for (int nf = 0; nf < 4; ++nf)
                    kf[nf] = kpk[base + ((size_t)((ktk * 4 + nf) * 2 + ks)) * 64 + l];
#pragma unroll
                for (int nf = 0; nf < 4; ++nf)
                    S[nf] = __builtin_amdgcn_mfma_f32_16x16x32_bf16(qf[mf][ks], kf[nf], S[nf], 0, 0, 0);
            }
            // online softmax per row
#pragma unroll
            for (int r = 0; r < 4; ++r) {
                float mt_ = fmaxf(fmaxf(S[0][r], S[1][r]), fmaxf(S[2][r], S[3][r]));
                for (int off = 1; off < 16; off <<= 1) mt_ = fmaxf(mt_, __shfl_xor(mt_, off, 64));
                float mnew = fmaxf(mrun[mf][r], mt_);
                float sc = __expf(mrun[mf][r] - mnew);
#pragma unroll
                for (int nf = 0; nf < 4; ++nf) O[mf][nf][r] *= sc;
                float ps = 0.f;
#pragma unroll
                for (int nf = 0; nf < 4; ++nf) {
                    float pp = __expf(S[nf][r] - mnew);
                    S[nf][r] = pp;
                    ps += pp;
                }
                for (int off = 1; off < 16; off <<= 1) ps += __shfl_xor(ps, off, 64);
                lrun[mf][r] = lrun[mf][r] * sc + ps;
                mrun[mf][r] = mnew;
            }
            // P -> LDS (bf16, swizzled) — wave-local rows
#pragma unroll
            for (int nf = 0; nf < 4; ++nf)
#pragma unroll
                for (int r = 0; r < 4; ++r) {
                    int row = w * 32 + mf * 16 + lk * 4 + r, col = nf * 16 + lr;
                    unsigned int byte = ((unsigned)(row * 64 + col) * 2) ^ (unsigned)((row & 7) << 4);
                    *(unsigned short*)(Pb + byte) = f2bf(S[nf][r]);
                }
        }
        // PV: reads only this wave's rows — no barrier needed
#pragma unroll
        for (int ks = 0; ks < 2; ++ks) {
            bf16x8s vf[4];
#pragma unroll
            for (int nf = 0; nf < 4; ++nf)
                vf[nf] = vpk[base + ((size_t)((ktk * 2 + ks) * 4 + nf)) * 64 + l];
#pragma unroll
            for (int mf = 0; mf < 2; ++mf) {
                int row = w * 32 + mf * 16 + lr;
                unsigned int byte = ((unsigned)(row * 64 + ks * 32 + lk * 8) * 2) ^ (unsigned)((row & 7) << 4);
                bf16x8s pa = *(const bf16x8s*)(Pb + byte);
#pragma unroll
                for (int nf = 0; nf < 4; ++nf)
                    O[mf][nf] = __builtin_amdgcn_mfma_f32_16x16x32_bf16(pa, vf[nf], O[mf][nf], 0, 0, 0);
            }
        }
    }

    // normalize -> LDS (bf16, swizzled) -> pack out (wave-local rows, no barrier)
#pragma unroll
    for (int mf = 0; mf < 2; ++mf)
#pragma unroll
        for (int r = 0; r < 4; ++r) {
            float inv = 1.f / lrun[mf][r];
#pragma unroll
            for (int nf = 0; nf < 4; ++nf) {
                int row = w * 32 + mf * 16 + lk * 4 + r, col = nf * 16 + lr;
                unsigned int byte = ((unsigned)(row * 64 + col) * 2) ^ (unsigned)((row & 7) << 4);
                *(unsigned short*)(Pb + byte) = f2bf(O[mf][nf][r] * inv);
            }
        }
    const int seq = sh >> 2, h = sh & 3;
#pragma unroll
    for (int mf = 0; mf < 2; ++mf)
#pragma unroll
        for (int ktd = 0; ktd < 2; ++ktd) {
            int row = w * 32 + mf * 16 + lr;
            unsigned int byte = ((unsigned)(row * 64 + ktd * 32 + lk * 8) * 2) ^ (unsigned)((row & 7) << 4);
            bf16x8s o = *(const bf16x8s*)(Pb + byte);
            size_t mtg = (size_t)seq * 16 + w * 2 + mf;
            opk[(mtg * 8 + h * 2 + ktd) * 64 + l] = o;
        }
}

// =====================================================================
// Proj GEMM: grid 1024 blocks x 512 threads; block = 64 rows x 256 cols via
// an in-block 2-phase nb loop. Wave = 1 m-tile x 4 n-tiles (acc[4], no LDS).
// Direct register epilogue.
// =====================================================================
__global__ __launch_bounds__(512) void gemm_proj_kernel(
    const bf16x8s* __restrict__ A,
    const float* __restrict__ x, const float* __restrict__ bo,
    float* __restrict__ out, int pass)
{
    const int tid = threadIdx.x;
    const int l = tid & 63, w = tid >> 6;       // w 0..7
    const int wm = w >> 1, wn = w & 1;          // wm 0..3 (16-row m-tiles), wn 0..1 (64-col strips)
    const int mb = blockIdx.x;                  // 1024 blocks, 64 rows each
    const bf16x8s* B = g_wpk[pass * 4 + 3];
    const int mt0 = mb * 4 + wm;

#pragma unroll 1
    for (int nb = 0; nb < 2; ++nb) {
        f32x4 acc[4];
#pragma unroll
        for (int nf = 0; nf < 4; ++nf) { f32x4 z = {0.f, 0.f, 0.f, 0.f}; acc[nf] = z; }

        const int nt0 = nb * 8 + wn * 4;
#pragma unroll
        for (int ks = 0; ks < 8; ++ks) {
            bf16x8s a = A[((size_t)mt0 * 8 + ks) * 64 + l];
            bf16x8s b[4];
#pragma unroll
            for (int nf = 0; nf < 4; ++nf) b[nf] = B[((size_t)(nt0 + nf) * 8 + ks) * 64 + l];
#pragma unroll
            for (int nf = 0; nf < 4; ++nf)
                acc[nf] = __builtin_amdgcn_mfma_f32_16x16x32_bf16(a, b[nf], acc[nf], 0, 0, 0);
        }

        // direct epilogue from registers: bias + ELU + residual
#pragma unroll
        for (int nf = 0; nf < 4; ++nf) {
            const int col = nb * 128 + wn * 64 + nf * 16 + (l & 15);
            const float bc = bo[col];
#pragma unroll
            for (int r = 0; r < 4; ++r) {
                int row = mb * 64 + wm * 16 + (l >> 4) * 4 + r;
                size_t prow = (pass == 0) ? (size_t)row
                                          : ((size_t)(row & 255) * NSEQ + (row >> 8));
                size_t addr = prow * DIM + col;
                float y = acc[nf][r] + bc;
                float e = 0.5f * (y > 0.f ? y : expm1f(y));
                if (pass == 0) out[addr] = x[addr] + e;
                else           out[addr] += e;
            }
        }
    }
}

// =====================================================================
extern "C" void kernel_launch(void* const* d_in, const int* in_sizes, int n_in,
                              void* d_out, int out_size, void* d_ws, size_t ws_size,
                              hipStream_t stream) {
    const float* x     = (const float*)d_in[0];
    const float* sin_i = (const float*)d_in[1];
    const float* cos_i = (const float*)d_in[2];
    const float* sin_j = (const float*)d_in[3];
    const float* cos_j = (const float*)d_in[4];
    const float* gia   = (const float*)d_in[5];
    const float* bia   = (const float*)d_in[6];
    const float* gib   = (const float*)d_in[7];
    const float* bib   = (const float*)d_in[8];
    const float* Wq_i  = (const float*)d_in[9];
    const float* Wkv_i = (const float*)d_in[10];
    const float* Wo_i  = (const float*)d_in[11];
    const float* bo_i  = (const float*)d_in[12];
    const float* gja   = (const float*)d_in[13];
    const float* bja   = (const float*)d_in[14];
    const float* gjb   = (const float*)d_in[15];
    const float* bjb   = (const float*)d_in[16];
    const float* Wq_j  = (const float*)d_in[17];
    const float* Wkv_j = (const float*)d_in[18];
    const float* Wo_j  = (const float*)d_in[19];
    const float* bo_j  = (const float*)d_in[20];

    float* out = (float*)d_out;

    char* base = (char*)d_ws;
    const size_t MB32 = 33554432;
    bf16x8s* buf0 = (bf16x8s*)(base);             // v
    bf16x8s* buf1 = (bf16x8s*)(base + MB32);      // o
    bf16x8s* buf2 = (bf16x8s*)(base + 2 * MB32);  // q
    bf16x8s* buf3 = (bf16x8s*)(base + 3 * MB32);  // k

    // pack all weights (gamma folded) + fold beta/gamma into bias/csum vectors
    wpack_all_kernel<<<dim3(32, 8), 256, 0, stream>>>(
        Wq_i, Wkv_i, Wo_i, Wq_j, Wkv_j, Wo_j, gia, gib, gja, gjb);
    bias_kernel<<<6, 256, 0, stream>>>(
        bia, bib, bja, bjb, gia, gib, gja, gjb, Wq_i, Wkv_i, Wq_j, Wkv_j);

    for (int pass = 0; pass < 2; ++pass) {
        const float* sin_t = pass ? sin_j : sin_i;
        const float* cos_t = pass ? cos_j : cos_i;
        const float* bo = pass ? bo_j : bo_i;

        // fused LN + QKV + RoPE + repack: q->buf2, k->buf3, v->buf0
        lnqkv_kernel<<<2048, 1024, 0, stream>>>(
            x, sin_t, cos_t, buf2, buf3, buf0, pass);
        // attn: q,k,v -> o (buf1)
        attn_kernel<<<1024, 512, 0, stream>>>(buf2, buf3, buf0, buf1);
        // proj + residual
        gemm_proj_kernel<<<1024, 512, 0, stream>>>(buf1, x, bo, out, pass);
    }
}